// Round 2
// baseline (74.407 us; speedup 1.0000x reference)
//
#include <hip/hip_runtime.h>

#define DIM 32
#define H1 64      // hidden units
#define XW 96      // 3*DIM input width
#define BLK 256

__global__ __launch_bounds__(BLK, 2) void mtn_fused(
    const int* __restrict__ uid, const int* __restrict__ iid,
    const float* __restrict__ Uw, const float* __restrict__ Qw,
    const float* __restrict__ Aw, const float* __restrict__ Bw,
    const float* __restrict__ W1, const float* __restrict__ b1g,
    const float* __restrict__ W2, const float* __restrict__ b2g,
    float* __restrict__ out, int batch)
{
    int i = blockIdx.x * BLK + threadIdx.x;
    if (i >= batch) return;

    int u_idx = uid[i];
    int q_idx = iid[i];

    const float4* up = (const float4*)(Uw + (long long)u_idx * DIM);
    const float4* qp = (const float4*)(Qw + (long long)q_idx * DIM);

    // x = [u | q | u*q], kept entirely in VGPRs
    float x[XW];
    float dot = 0.f;
#pragma unroll
    for (int k = 0; k < DIM / 4; ++k) {
        float4 uv = up[k];
        float4 qv = qp[k];
        x[4*k+0] = uv.x; x[4*k+1] = uv.y; x[4*k+2] = uv.z; x[4*k+3] = uv.w;
        x[DIM+4*k+0] = qv.x; x[DIM+4*k+1] = qv.y; x[DIM+4*k+2] = qv.z; x[DIM+4*k+3] = qv.w;
        float p0 = uv.x * qv.x;
        float p1 = uv.y * qv.y;
        float p2 = uv.z * qv.z;
        float p3 = uv.w * qv.w;
        x[2*DIM+4*k+0] = p0; x[2*DIM+4*k+1] = p1;
        x[2*DIM+4*k+2] = p2; x[2*DIM+4*k+3] = p3;
        dot += (p0 + p1) + (p2 + p3);
    }

    float pred = dot + Aw[u_idx] + Bw[q_idx];
    out[i] = pred;

    // MLP: h = relu(x @ W1^T + b1); score = relu(h . W2 + b2)
    // Weights read with wave-uniform addresses -> scalar (SGPR) loads,
    // FMAs are v_fma_f32 vdst, s_weight, v_x : no LDS, no per-lane load.
    float score = b2g[0];
#pragma unroll 4
    for (int j = 0; j < H1; ++j) {
        const float* __restrict__ w = W1 + j * XW;
        float a0 = b1g[j], a1 = 0.f, a2 = 0.f;
#pragma unroll
        for (int k = 0; k < XW; k += 3) {
            a0 = fmaf(x[k+0], w[k+0], a0);
            a1 = fmaf(x[k+1], w[k+1], a1);
            a2 = fmaf(x[k+2], w[k+2], a2);
        }
        float h = fmaxf(a0 + a1 + a2, 0.f);
        score = fmaf(h, W2[j], score);
    }
    out[batch + i] = fmaxf(score, 0.f);
}

extern "C" void kernel_launch(void* const* d_in, const int* in_sizes, int n_in,
                              void* d_out, int out_size, void* d_ws, size_t ws_size,
                              hipStream_t stream) {
    const int*   uid = (const int*)  d_in[0];
    const int*   iid = (const int*)  d_in[1];
    const float* Uw  = (const float*)d_in[2];
    const float* Qw  = (const float*)d_in[3];
    const float* Aw  = (const float*)d_in[4];
    const float* Bw  = (const float*)d_in[5];
    const float* W1  = (const float*)d_in[6];
    const float* b1  = (const float*)d_in[7];
    const float* W2  = (const float*)d_in[8];
    const float* b2  = (const float*)d_in[9];
    float* out = (float*)d_out;
    int batch = in_sizes[0];
    int blocks = (batch + BLK - 1) / BLK;
    hipLaunchKernelGGL(mtn_fused, dim3(blocks), dim3(BLK), 0, stream,
                       uid, iid, Uw, Qw, Aw, Bw, W1, b1, W2, b2, out, batch);
}

// Round 3
// 54.233 us; speedup vs baseline: 1.3720x; 1.3720x over previous
//
#include <hip/hip_runtime.h>

#define DIM 32
#define H1 64      // hidden units
#define XW 96      // 3*DIM input width
#define BLK 256

// ---------- tiny pre-kernel: W1 [64][96] -> W1T [96][64] in d_ws ----------
__global__ __launch_bounds__(256) void transpose_w1(const float* __restrict__ W1,
                                                    float* __restrict__ W1T) {
    int t = blockIdx.x * 256 + threadIdx.x;
    if (t < H1 * XW) {
        int j = t / XW;   // row in W1 (hidden unit)
        int k = t % XW;   // col in W1 (input feature)
        W1T[k * H1 + j] = W1[t];
    }
}

// ---------- main fused kernel: accumulator-stationary MLP ----------
__global__ __launch_bounds__(BLK) void mtn_fused(
    const int* __restrict__ uid, const int* __restrict__ iid,
    const float* __restrict__ Uw, const float* __restrict__ Qw,
    const float* __restrict__ Aw, const float* __restrict__ Bw,
    const float* __restrict__ W1T, const float* __restrict__ b1g,
    const float* __restrict__ W2, const float* __restrict__ b2g,
    float* __restrict__ out, int batch)
{
    int i = blockIdx.x * BLK + threadIdx.x;
    if (i >= batch) return;

    int u_idx = uid[i];
    int q_idx = iid[i];

    const float4* up = (const float4*)(Uw + (long long)u_idx * DIM);
    const float4* qp = (const float4*)(Qw + (long long)q_idx * DIM);

    // 64 accumulators, init from b1 (wave-uniform scalar float4 loads)
    float acc[H1];
    {
        const float4* bt = (const float4*)b1g;
#pragma unroll
        for (int j4 = 0; j4 < H1 / 4; ++j4) {
            float4 b = bt[j4];
            acc[4*j4+0] = b.x; acc[4*j4+1] = b.y;
            acc[4*j4+2] = b.z; acc[4*j4+3] = b.w;
        }
    }

    float dot = 0.f;

    // Stream x = [u | q | u*q] one element at a time; each element is
    // consumed by all 64 hidden units then discarded (short live range).
    // Weights come from transposed W1T: column k is 64 contiguous floats,
    // read as 16 wave-uniform float4 -> s_load_dwordx4 (scalar pipe).
#pragma unroll 1
    for (int c = 0; c < DIM / 4; ++c) {
        float4 uv = up[c];
        float4 qv = qp[c];
        float ue[4] = {uv.x, uv.y, uv.z, uv.w};
        float qe[4] = {qv.x, qv.y, qv.z, qv.w};
#pragma unroll
        for (int e = 0; e < 4; ++e) {
            int k = 4 * c + e;
            float xu = ue[e];
            float xq = qe[e];
            float xp = xu * xq;
            dot += xp;
            const float4* wu = (const float4*)(W1T + (long long)k * H1);
            const float4* wq = (const float4*)(W1T + (long long)(DIM + k) * H1);
            const float4* wp = (const float4*)(W1T + (long long)(2 * DIM + k) * H1);
#pragma unroll
            for (int j4 = 0; j4 < H1 / 4; ++j4) {
                float4 a = wu[j4];
                float4 b = wq[j4];
                float d = 0.f; // placeholder to keep style; real loads below
                float4 p = wp[j4];
                acc[4*j4+0] = fmaf(xu, a.x, acc[4*j4+0]);
                acc[4*j4+1] = fmaf(xu, a.y, acc[4*j4+1]);
                acc[4*j4+2] = fmaf(xu, a.z, acc[4*j4+2]);
                acc[4*j4+3] = fmaf(xu, a.w, acc[4*j4+3]);
                acc[4*j4+0] = fmaf(xq, b.x, acc[4*j4+0]);
                acc[4*j4+1] = fmaf(xq, b.y, acc[4*j4+1]);
                acc[4*j4+2] = fmaf(xq, b.z, acc[4*j4+2]);
                acc[4*j4+3] = fmaf(xq, b.w, acc[4*j4+3]);
                acc[4*j4+0] = fmaf(xp, p.x, acc[4*j4+0]);
                acc[4*j4+1] = fmaf(xp, p.y, acc[4*j4+1]);
                acc[4*j4+2] = fmaf(xp, p.z, acc[4*j4+2]);
                acc[4*j4+3] = fmaf(xp, p.w, acc[4*j4+3]);
                (void)d;
            }
        }
    }

    float pred = dot + Aw[u_idx] + Bw[q_idx];
    out[i] = pred;

    // score = relu( sum_j relu(acc[j]) * W2[j] + b2 )
    float score = b2g[0];
    {
        const float4* w2t = (const float4*)W2;
#pragma unroll
        for (int j4 = 0; j4 < H1 / 4; ++j4) {
            float4 w = w2t[j4];
            score = fmaf(fmaxf(acc[4*j4+0], 0.f), w.x, score);
            score = fmaf(fmaxf(acc[4*j4+1], 0.f), w.y, score);
            score = fmaf(fmaxf(acc[4*j4+2], 0.f), w.z, score);
            score = fmaf(fmaxf(acc[4*j4+3], 0.f), w.w, score);
        }
    }
    out[batch + i] = fmaxf(score, 0.f);
}

extern "C" void kernel_launch(void* const* d_in, const int* in_sizes, int n_in,
                              void* d_out, int out_size, void* d_ws, size_t ws_size,
                              hipStream_t stream) {
    const int*   uid = (const int*)  d_in[0];
    const int*   iid = (const int*)  d_in[1];
    const float* Uw  = (const float*)d_in[2];
    const float* Qw  = (const float*)d_in[3];
    const float* Aw  = (const float*)d_in[4];
    const float* Bw  = (const float*)d_in[5];
    const float* W1  = (const float*)d_in[6];
    const float* b1  = (const float*)d_in[7];
    const float* W2  = (const float*)d_in[8];
    const float* b2  = (const float*)d_in[9];
    float* out = (float*)d_out;
    float* W1T = (float*)d_ws;   // 96*64*4 = 24 KB scratch
    int batch = in_sizes[0];

    hipLaunchKernelGGL(transpose_w1, dim3((H1 * XW + 255) / 256), dim3(256), 0, stream,
                       W1, W1T);

    int blocks = (batch + BLK - 1) / BLK;
    hipLaunchKernelGGL(mtn_fused, dim3(blocks), dim3(BLK), 0, stream,
                       uid, iid, Uw, Qw, Aw, Bw, W1T, b1, W2, b2, out, batch);
}

// Round 4
// 26.963 us; speedup vs baseline: 2.7596x; 2.0114x over previous
//
#include <hip/hip_runtime.h>

#define DIM 32
#define H1 64
#define XW 96
#define BLK 256
#define SPB 256          // samples per block
#define RS 104           // LDS row stride in bf16 elems (208 B: 16B-aligned, 2-way banks)

typedef __attribute__((ext_vector_type(8))) short bf16x8;
typedef __attribute__((ext_vector_type(4))) float f32x4;

__device__ __forceinline__ unsigned short f2bf(float f) {
    unsigned u = __float_as_uint(f);
    unsigned r = ((u >> 16) & 1u) + 0x7fffu;   // round-to-nearest-even
    return (unsigned short)((u + r) >> 16);
}

// Pack W1 [64][96] into MFMA B-fragment order (bf16):
// Bpack[((ks*4+n)*64 + l)*8 + e] = bf16( W1[ n*16+(l&15) ][ ks*32 + (l>>4)*8 + e ] )
__global__ __launch_bounds__(256) void prep_pack(const float* __restrict__ W1,
                                                 unsigned short* __restrict__ Bpack) {
    for (int idx = threadIdx.x; idx < 3 * 4 * 64 * 8; idx += 256) {
        int e  = idx & 7;
        int l  = (idx >> 3) & 63;
        int n  = (idx >> 9) & 3;
        int ks = idx >> 11;
        int j = n * 16 + (l & 15);
        int k = ks * 32 + ((l >> 4) << 3) + e;
        Bpack[idx] = f2bf(W1[j * 96 + k]);
    }
}

__global__ __launch_bounds__(BLK, 2) void mtn_fused(
    const int* __restrict__ uid, const int* __restrict__ iid,
    const float* __restrict__ Uw, const float* __restrict__ Qw,
    const float* __restrict__ Aw, const float* __restrict__ Bw,
    const unsigned short* __restrict__ Bpack, const float* __restrict__ b1g,
    const float* __restrict__ W2, const float* __restrict__ b2g,
    float* __restrict__ out, int batch)
{
    __shared__ unsigned short Xs[SPB][RS];   // 53 KB

    // ---------------- phase 1: gather, predictions, stage x in LDS ----------
    int i = blockIdx.x * SPB + threadIdx.x;
    bool valid = (i < batch);
    int u_idx = valid ? uid[i] : 0;
    int q_idx = valid ? iid[i] : 0;

    const float4* up = (const float4*)(Uw + (long long)u_idx * DIM);
    const float4* qp = (const float4*)(Qw + (long long)q_idx * DIM);

    unsigned short* xr = &Xs[threadIdx.x][0];
    float dot = 0.f;
#pragma unroll
    for (int c = 0; c < DIM / 4; ++c) {
        float4 uv = up[c];
        float4 qv = qp[c];
        float p0 = uv.x * qv.x, p1 = uv.y * qv.y, p2 = uv.z * qv.z, p3 = uv.w * qv.w;
        dot += (p0 + p1) + (p2 + p3);
        *(ushort4*)&xr[4 * c]            = make_ushort4(f2bf(uv.x), f2bf(uv.y), f2bf(uv.z), f2bf(uv.w));
        *(ushort4*)&xr[DIM + 4 * c]      = make_ushort4(f2bf(qv.x), f2bf(qv.y), f2bf(qv.z), f2bf(qv.w));
        *(ushort4*)&xr[2 * DIM + 4 * c]  = make_ushort4(f2bf(p0), f2bf(p1), f2bf(p2), f2bf(p3));
    }
    if (valid) out[i] = dot + Aw[u_idx] + Bw[q_idx];

    __syncthreads();

    // ---------------- phase 2: MFMA MLP ----------------
    int wave = threadIdx.x >> 6;
    int lane = threadIdx.x & 63;
    int lr = lane & 15;    // A row-in-tile / B,C column
    int lg = lane >> 4;    // k-group / C row-group

    // entire W1 as B-fragments, resident in 48 VGPRs (12 KB, L1-hot)
    bf16x8 bfrag[3][4];
    {
        const bf16x8* bp = (const bf16x8*)Bpack;
#pragma unroll
        for (int ks = 0; ks < 3; ++ks)
#pragma unroll
            for (int n = 0; n < 4; ++n)
                bfrag[ks][n] = bp[(ks * 4 + n) * 64 + lane];
    }
    float w2l[4], b1l[4];
#pragma unroll
    for (int n = 0; n < 4; ++n) {
        w2l[n] = W2[n * 16 + lr];
        b1l[n] = b1g[n * 16 + lr];
    }
    float b2v = b2g[0];

    int sbase = blockIdx.x * SPB + wave * 64;
#pragma unroll 1
    for (int m = 0; m < 4; ++m) {
        int rowb = wave * 64 + m * 16 + lr;
        bf16x8 a0 = *(const bf16x8*)&Xs[rowb][0 * 32 + lg * 8];
        bf16x8 a1 = *(const bf16x8*)&Xs[rowb][1 * 32 + lg * 8];
        bf16x8 a2 = *(const bf16x8*)&Xs[rowb][2 * 32 + lg * 8];

        f32x4 c0 = {b1l[0], b1l[0], b1l[0], b1l[0]};
        f32x4 c1 = {b1l[1], b1l[1], b1l[1], b1l[1]};
        f32x4 c2 = {b1l[2], b1l[2], b1l[2], b1l[2]};
        f32x4 c3 = {b1l[3], b1l[3], b1l[3], b1l[3]};

        c0 = __builtin_amdgcn_mfma_f32_16x16x32_bf16(a0, bfrag[0][0], c0, 0, 0, 0);
        c1 = __builtin_amdgcn_mfma_f32_16x16x32_bf16(a0, bfrag[0][1], c1, 0, 0, 0);
        c2 = __builtin_amdgcn_mfma_f32_16x16x32_bf16(a0, bfrag[0][2], c2, 0, 0, 0);
        c3 = __builtin_amdgcn_mfma_f32_16x16x32_bf16(a0, bfrag[0][3], c3, 0, 0, 0);
        c0 = __builtin_amdgcn_mfma_f32_16x16x32_bf16(a1, bfrag[1][0], c0, 0, 0, 0);
        c1 = __builtin_amdgcn_mfma_f32_16x16x32_bf16(a1, bfrag[1][1], c1, 0, 0, 0);
        c2 = __builtin_amdgcn_mfma_f32_16x16x32_bf16(a1, bfrag[1][2], c2, 0, 0, 0);
        c3 = __builtin_amdgcn_mfma_f32_16x16x32_bf16(a1, bfrag[1][3], c3, 0, 0, 0);
        c0 = __builtin_amdgcn_mfma_f32_16x16x32_bf16(a2, bfrag[2][0], c0, 0, 0, 0);
        c1 = __builtin_amdgcn_mfma_f32_16x16x32_bf16(a2, bfrag[2][1], c1, 0, 0, 0);
        c2 = __builtin_amdgcn_mfma_f32_16x16x32_bf16(a2, bfrag[2][2], c2, 0, 0, 0);
        c3 = __builtin_amdgcn_mfma_f32_16x16x32_bf16(a2, bfrag[2][3], c3, 0, 0, 0);

        // layer 2: score = relu( sum_j relu(h_j)*W2[j] + b2 )
        float tot[4];
#pragma unroll
        for (int r = 0; r < 4; ++r) {
            float p = fmaxf(c0[r], 0.f) * w2l[0] + fmaxf(c1[r], 0.f) * w2l[1]
                    + fmaxf(c2[r], 0.f) * w2l[2] + fmaxf(c3[r], 0.f) * w2l[3];
            p += __shfl_xor(p, 1);
            p += __shfl_xor(p, 2);
            p += __shfl_xor(p, 4);
            p += __shfl_xor(p, 8);
            tot[r] = p;
        }
        if (lr < 4) {
            int s = sbase + m * 16 + lg * 4 + lr;
            if (s < batch) out[batch + s] = fmaxf(tot[lr] + b2v, 0.f);
        }
    }
}

extern "C" void kernel_launch(void* const* d_in, const int* in_sizes, int n_in,
                              void* d_out, int out_size, void* d_ws, size_t ws_size,
                              hipStream_t stream) {
    const int*   uid = (const int*)  d_in[0];
    const int*   iid = (const int*)  d_in[1];
    const float* Uw  = (const float*)d_in[2];
    const float* Qw  = (const float*)d_in[3];
    const float* Aw  = (const float*)d_in[4];
    const float* Bw  = (const float*)d_in[5];
    const float* W1  = (const float*)d_in[6];
    const float* b1  = (const float*)d_in[7];
    const float* W2  = (const float*)d_in[8];
    const float* b2  = (const float*)d_in[9];
    float* out = (float*)d_out;
    unsigned short* Bpack = (unsigned short*)d_ws;   // 12 KB
    int batch = in_sizes[0];

    hipLaunchKernelGGL(prep_pack, dim3(1), dim3(256), 0, stream, W1, Bpack);

    int blocks = (batch + SPB - 1) / SPB;
    hipLaunchKernelGGL(mtn_fused, dim3(blocks), dim3(BLK), 0, stream,
                       uid, iid, Uw, Qw, Aw, Bw, Bpack, b1, W2, b2, out, batch);
}